// Round 2
// baseline (352.154 us; speedup 1.0000x reference)
//
#include <hip/hip_runtime.h>
#include <math.h>

#define DIM   4096
#define NH    32
#define NKV   8
#define HD    128
#define KVBLK 256
#define TOPK  16
#define NCHUNK 64                    // 64 chunks of 64 positions
#define SCALE 0.08838834764831845f   // 1/sqrt(128)

// workspace layout (float offsets)
#define WS_Q   0        // 4096
#define WS_K   4096     // 1024
#define WS_V   5120     // 1024
#define WS_M   6144     // 32*64
#define WS_L   8192     // 32*64
#define WS_O   10240    // 32*64*128
#define WS_AO  272384   // 4096
// total 276480 floats ~ 1.08 MB

// ---------------------------------------------------------------------------
// K1: fused QKV GEMV + RoPE. 6144 rows (q:0..4095, k:4096..5119, v:5120..6143).
// One wave per (even,odd) ROW PAIR -> RoPE applied in-register, no LDS/barrier.
// grid = 768 blocks x 4 waves = 3072 pairs.
// ---------------------------------------------------------------------------
__global__ __launch_bounds__(256) void qkv_rope_kernel(
    const float* __restrict__ x,
    const float* __restrict__ wq,
    const float* __restrict__ wk,
    const float* __restrict__ wv,
    const float* __restrict__ cvec,
    const float* __restrict__ svec,
    float* __restrict__ ws)
{
  const int tid  = threadIdx.x;
  const int wave = tid >> 6;
  const int lane = tid & 63;
  const int pair = blockIdx.x * 4 + wave;   // 0..3071
  const int row_e = pair * 2;               // even row (pairs never straddle matrix bounds)

  const float* W;
  int r;
  if (row_e < 4096)      { W = wq; r = row_e; }
  else if (row_e < 5120) { W = wk; r = row_e - 4096; }
  else                   { W = wv; r = row_e - 5120; }

  const float4* we4 = (const float4*)(W + (size_t)r * DIM);
  const float4* wo4 = (const float4*)(W + (size_t)(r + 1) * DIM);
  const float4* x4  = (const float4*)x;

  float acc_e = 0.f, acc_o = 0.f;
#pragma unroll 8
  for (int i = 0; i < 16; ++i) {
    const float4 a  = x4[lane + i * 64];
    const float4 be = we4[lane + i * 64];
    const float4 bo = wo4[lane + i * 64];
    acc_e += a.x * be.x + a.y * be.y + a.z * be.z + a.w * be.w;
    acc_o += a.x * bo.x + a.y * bo.y + a.z * bo.z + a.w * bo.w;
  }
#pragma unroll
  for (int off = 32; off > 0; off >>= 1) {
    acc_e += __shfl_xor(acc_e, off, 64);
    acc_o += __shfl_xor(acc_o, off, 64);
  }

  if (lane == 0) {
    const float xe = acc_e, xo = acc_o;
    if (row_e < 5120) {               // q or k row pair: apply RoPE
      const int j   = (row_e & (HD - 1)) >> 1;
      const float c = cvec[j], s = svec[j];
      const float oe = xe * c - xo * s;
      const float oo = xe * s + xo * c;
      if (row_e < 4096) {
        ws[WS_Q + row_e]     = oe;
        ws[WS_Q + row_e + 1] = oo;
      } else {
        ws[WS_K + row_e - 4096] = oe;
        ws[WS_K + row_e - 4095] = oo;
      }
    } else {                          // v row pair: passthrough
      ws[WS_V + row_e - 5120] = xe;
      ws[WS_V + row_e - 5119] = xo;
    }
  }
}

// ---------------------------------------------------------------------------
// K2: flash-decode partials. grid = (64 chunks of 64 positions, 8 kv heads).
// K and V staged into SEPARATE 32KB LDS buffers up front (all global loads in
// flight together, single barrier). Wave w handles q head kvh*4+w; each lane
// owns one position.
// ---------------------------------------------------------------------------
__global__ __launch_bounds__(256) void attn_partial_kernel(
    const float* __restrict__ kc,
    const float* __restrict__ vc,
    const int*   __restrict__ bidx,
    float* __restrict__ ws)
{
  const int chunk = blockIdx.x;   // 0..63
  const int kvh   = blockIdx.y;   // 0..7
  const int tid   = threadIdx.x;
  const int wave  = tid >> 6;
  const int lane  = tid & 63;

  __shared__ float4 k4[64 * 32];   // 32 KB, xor-swizzled
  __shared__ float4 v4s[64 * 32];  // 32 KB, linear

  const int cb      = bidx[chunk >> 2];     // 4 chunks per cache block
  const int posbase = (chunk & 3) * 64;
  // element (pos,d) of head kvh in cache block cb: pos stride = 256 float4
  const size_t basef4 = ((((size_t)cb * KVBLK + posbase) * NKV + kvh) * HD) / 4;
  const float4* ksrc = (const float4*)kc + basef4;
  const float4* vsrc = (const float4*)vc + basef4;

  // ---- stage K (swizzled) and V (linear); issue everything, one barrier ----
#pragma unroll
  for (int i = 0; i < 8; ++i) {
    const int idx = tid + i * 256;
    const int p   = idx >> 5;
    const int d4  = idx & 31;
    k4[p * 32 + (d4 ^ (p & 31))] = ksrc[(size_t)p * 256 + d4];
  }
#pragma unroll
  for (int i = 0; i < 8; ++i) {
    const int idx = tid + i * 256;
    const int p   = idx >> 5;
    const int d4  = idx & 31;
    v4s[p * 32 + d4] = vsrc[(size_t)p * 256 + d4];
  }
  __syncthreads();

  // ---- scores: lane owns position p0 = lane ----
  const int qh = kvh * 4 + wave;
  const float4* qg4 = (const float4*)(ws + WS_Q + (size_t)qh * HD);

  float s0 = 0.f;
  const int p0 = lane;
#pragma unroll
  for (int d4 = 0; d4 < 32; ++d4) {
    const float4 qv = qg4[d4];  // wave-uniform -> broadcast, L1-hot
    const float4 k0 = k4[p0 * 32 + (d4 ^ (p0 & 31))];
    s0 += qv.x * k0.x + qv.y * k0.y + qv.z * k0.z + qv.w * k0.w;
  }
  s0 *= SCALE;

  // wave softmax over this chunk's 64 scores
  float m = s0;
#pragma unroll
  for (int off = 32; off > 0; off >>= 1)
    m = fmaxf(m, __shfl_xor(m, off, 64));
  const float e0 = __expf(s0 - m);
  float l = e0;
#pragma unroll
  for (int off = 32; off > 0; off >>= 1)
    l += __shfl_xor(l, off, 64);

  // ---- PV: lane owns dims 2*lane, 2*lane+1; e broadcast via shfl ----
  float2 o = make_float2(0.f, 0.f);
  const float2* v2 = (const float2*)v4s;
#pragma unroll 8
  for (int t = 0; t < 64; ++t) {
    const float e = __shfl(e0, t, 64);
    const float2 vv = v2[(size_t)t * 64 + lane];
    o.x += e * vv.x;
    o.y += e * vv.y;
  }

  const int pc = qh * NCHUNK + chunk;
  if (lane == 0) {
    ws[WS_M + pc] = m;
    ws[WS_L + pc] = l;
  }
  ((float2*)(ws + WS_O + (size_t)pc * HD))[lane] = o;
}

// ---------------------------------------------------------------------------
// K3: combine 64 chunk-partials per q head + the fresh token, normalize.
// grid = 32 heads, block = 128 threads (one per dim).
// ---------------------------------------------------------------------------
__global__ __launch_bounds__(128) void attn_reduce_kernel(float* __restrict__ ws)
{
  const int qh  = blockIdx.x;
  const int d   = threadIdx.x;
  const int kvh = qh >> 2;

  __shared__ float red[128];
  red[d] = ws[WS_Q + qh * HD + d] * ws[WS_K + kvh * HD + d];
  __syncthreads();
  for (int off = 64; off > 0; off >>= 1) {
    if (d < off) red[d] += red[d + off];
    __syncthreads();
  }
  const float s_new = red[0] * SCALE;

  float m_g = s_new;
  for (int c = 0; c < NCHUNK; ++c)
    m_g = fmaxf(m_g, ws[WS_M + qh * NCHUNK + c]);

  const float w_new = __expf(s_new - m_g);
  float l_g = w_new;
  float o_d = w_new * ws[WS_V + kvh * HD + d];
  for (int c = 0; c < NCHUNK; ++c) {
    const float mc = ws[WS_M + qh * NCHUNK + c];
    const float lc = ws[WS_L + qh * NCHUNK + c];
    const float w  = __expf(mc - m_g);
    l_g += lc * w;
    o_d += w * ws[WS_O + (size_t)(qh * NCHUNK + c) * HD + d];
  }
  ws[WS_AO + qh * HD + d] = o_d / l_g;
}

// ---------------------------------------------------------------------------
// K4: output projection GEMV, row pair per wave. grid = 512 blocks.
// ---------------------------------------------------------------------------
__global__ __launch_bounds__(256) void oproj_kernel(
    const float* __restrict__ wo,
    const float* __restrict__ ws,
    float* __restrict__ out)
{
  const int tid  = threadIdx.x;
  const int wave = tid >> 6;
  const int lane = tid & 63;
  const int pair = blockIdx.x * 4 + wave;   // 0..2047
  const int r0   = pair * 2;

  const float4* w04 = (const float4*)(wo + (size_t)r0 * DIM);
  const float4* w14 = (const float4*)(wo + (size_t)(r0 + 1) * DIM);
  const float4* a4  = (const float4*)(ws + WS_AO);

  float acc0 = 0.f, acc1 = 0.f;
#pragma unroll 8
  for (int i = 0; i < 16; ++i) {
    const float4 a  = a4[lane + i * 64];
    const float4 b0 = w04[lane + i * 64];
    const float4 b1 = w14[lane + i * 64];
    acc0 += a.x * b0.x + a.y * b0.y + a.z * b0.z + a.w * b0.w;
    acc1 += a.x * b1.x + a.y * b1.y + a.z * b1.z + a.w * b1.w;
  }
#pragma unroll
  for (int off = 32; off > 0; off >>= 1) {
    acc0 += __shfl_xor(acc0, off, 64);
    acc1 += __shfl_xor(acc1, off, 64);
  }

  if (lane == 0) {
    out[r0]     = acc0;
    out[r0 + 1] = acc1;
  }
}

// ---------------------------------------------------------------------------
extern "C" void kernel_launch(void* const* d_in, const int* in_sizes, int n_in,
                              void* d_out, int out_size, void* d_ws, size_t ws_size,
                              hipStream_t stream)
{
  const float* x    = (const float*)d_in[0];
  const float* fcos = (const float*)d_in[1];
  const float* fsin = (const float*)d_in[2];
  const float* wq   = (const float*)d_in[3];
  const float* wk   = (const float*)d_in[4];
  const float* wv   = (const float*)d_in[5];
  const float* wo   = (const float*)d_in[6];
  const float* kc   = (const float*)d_in[7];
  const float* vc   = (const float*)d_in[8];
  const int*   bidx = (const int*)d_in[9];
  float* out = (float*)d_out;
  float* ws  = (float*)d_ws;

  qkv_rope_kernel<<<768, 256, 0, stream>>>(x, wq, wk, wv, fcos, fsin, ws);
  attn_partial_kernel<<<dim3(NCHUNK, NKV), 256, 0, stream>>>(kc, vc, bidx, ws);
  attn_reduce_kernel<<<32, 128, 0, stream>>>(ws);
  oproj_kernel<<<512, 256, 0, stream>>>(wo, ws, out);
}

// Round 3
// 333.121 us; speedup vs baseline: 1.0571x; 1.0571x over previous
//
#include <hip/hip_runtime.h>
#include <math.h>

#define DIM   4096
#define NH    32
#define NKV   8
#define HD    128
#define KVBLK 256
#define TOPK  16
#define NCHUNK 64                    // 64 chunks of 64 positions
#define SCALE 0.08838834764831845f   // 1/sqrt(128)

// workspace layout (float offsets)
#define WS_Q   0        // 4096
#define WS_K   4096     // 1024
#define WS_V   5120     // 1024
#define WS_M   6144     // 32*64
#define WS_L   8192     // 32*64
#define WS_O   10240    // 32*64*128
#define WS_AO  272384   // 4096

typedef float f4v __attribute__((ext_vector_type(4)));

static __device__ __forceinline__ f4v ntload4(const float* p) {
  return __builtin_nontemporal_load((const f4v*)p);
}

// ---------------------------------------------------------------------------
// K1: fused QKV GEMV + RoPE. One wave per (even,odd) row pair; RoPE in-register.
// grid = 768 blocks x 4 waves = 3072 pairs (q rows 0..4095, k 4096..5119,
// v 5120..6143). Weights streamed nontemporal (read-once).
// ---------------------------------------------------------------------------
__global__ __launch_bounds__(256) void qkv_rope_kernel(
    const float* __restrict__ x,
    const float* __restrict__ wq,
    const float* __restrict__ wk,
    const float* __restrict__ wv,
    const float* __restrict__ cvec,
    const float* __restrict__ svec,
    float* __restrict__ ws)
{
  const int tid  = threadIdx.x;
  const int wave = tid >> 6;
  const int lane = tid & 63;
  const int pair = blockIdx.x * 4 + wave;   // 0..3071
  const int row_e = pair * 2;

  const float* W;
  int r;
  if (row_e < 4096)      { W = wq; r = row_e; }
  else if (row_e < 5120) { W = wk; r = row_e - 4096; }
  else                   { W = wv; r = row_e - 5120; }

  const float* we = W + (size_t)r * DIM;
  const float* wo = W + (size_t)(r + 1) * DIM;
  const f4v*   x4 = (const f4v*)x;

  f4v ve = (f4v)0.f, vo = (f4v)0.f;
#pragma unroll 8
  for (int i = 0; i < 16; ++i) {
    const int o = (lane + i * 64) * 4;
    const f4v a  = x4[lane + i * 64];
    const f4v be = ntload4(we + o);
    const f4v bo = ntload4(wo + o);
    ve += a * be;
    vo += a * bo;
  }
  float acc_e = ve.x + ve.y + ve.z + ve.w;
  float acc_o = vo.x + vo.y + vo.z + vo.w;
#pragma unroll
  for (int off = 32; off > 0; off >>= 1) {
    acc_e += __shfl_xor(acc_e, off, 64);
    acc_o += __shfl_xor(acc_o, off, 64);
  }

  if (lane == 0) {
    const float xe = acc_e, xo = acc_o;
    if (row_e < 5120) {               // q or k pair: RoPE
      const int j   = (row_e & (HD - 1)) >> 1;
      const float c = cvec[j], s = svec[j];
      const float oe = xe * c - xo * s;
      const float oo = xe * s + xo * c;
      if (row_e < 4096) {
        ws[WS_Q + row_e]     = oe;
        ws[WS_Q + row_e + 1] = oo;
      } else {
        ws[WS_K + row_e - 4096] = oe;
        ws[WS_K + row_e - 4095] = oo;
      }
    } else {                          // v pair: passthrough
      ws[WS_V + row_e - 5120] = xe;
      ws[WS_V + row_e - 5119] = xo;
    }
  }
}

// ---------------------------------------------------------------------------
// K2: flash-decode partials. grid = (64 chunks of 64 pos, 8 kv heads).
// K (xor-swizzled) + V (linear) + q staged to LDS up front, single barrier.
// Wave w handles q head kvh*4+w; lane owns one position for scores.
// PV: lane-halves own float4 dim groups -> conflict-free ds_read_b128.
// ---------------------------------------------------------------------------
__global__ __launch_bounds__(256) void attn_partial_kernel(
    const float* __restrict__ kc,
    const float* __restrict__ vc,
    const int*   __restrict__ bidx,
    float* __restrict__ ws)
{
  const int chunk = blockIdx.x;   // 0..63
  const int kvh   = blockIdx.y;   // 0..7
  const int tid   = threadIdx.x;
  const int wave  = tid >> 6;
  const int lane  = tid & 63;

  __shared__ f4v k4[64 * 32];    // 32 KB, xor-swizzled
  __shared__ f4v v4s[64 * 32];   // 32 KB, linear
  __shared__ f4v sq4[4 * 32];    // 2 KB: q for the 4 heads of this kv group

  const int cb      = bidx[chunk >> 2];     // 4 chunks per cache block
  const int posbase = (chunk & 3) * 64;
  const size_t basef = (((size_t)cb * KVBLK + posbase) * NKV + kvh) * HD;
  const float* ksrc = kc + basef;
  const float* vsrc = vc + basef;

  // ---- stage K (swizzled), V (linear), q; one barrier ----
#pragma unroll
  for (int i = 0; i < 8; ++i) {
    const int idx = tid + i * 256;
    const int p   = idx >> 5;
    const int d4  = idx & 31;
    k4[p * 32 + (d4 ^ (p & 31))] = ntload4(ksrc + (size_t)p * 1024 + d4 * 4);
  }
#pragma unroll
  for (int i = 0; i < 8; ++i) {
    const int idx = tid + i * 256;
    const int p   = idx >> 5;
    const int d4  = idx & 31;
    v4s[p * 32 + d4] = ntload4(vsrc + (size_t)p * 1024 + d4 * 4);
  }
  if (tid < 128)
    sq4[tid] = ((const f4v*)(ws + WS_Q))[kvh * 128 + tid];
  __syncthreads();

  // ---- scores: lane owns position t = lane ----
  float s0 = 0.f;
  {
    f4v sacc = (f4v)0.f;
    const int p0 = lane;
#pragma unroll
    for (int d4 = 0; d4 < 32; ++d4) {
      const f4v qv = sq4[wave * 32 + d4];               // wave-uniform broadcast
      const f4v k0 = k4[p0 * 32 + (d4 ^ (p0 & 31))];    // conflict-free
      sacc += qv * k0;
    }
    s0 = (sacc.x + sacc.y + sacc.z + sacc.w) * SCALE;
  }

  // wave softmax over this chunk's 64 scores
  float m = s0;
#pragma unroll
  for (int off = 32; off > 0; off >>= 1)
    m = fmaxf(m, __shfl_xor(m, off, 64));
  const float e0 = __expf(s0 - m);
  float l = e0;
#pragma unroll
  for (int off = 32; off > 0; off >>= 1)
    l += __shfl_xor(l, off, 64);

  // ---- PV: half-wave h owns t in [32h, 32h+32); lane owns dims 4*(lane&31).. ----
  const int half = lane >> 5;
  const int l32  = lane & 31;
  f4v o = (f4v)0.f;
#pragma unroll 8
  for (int i = 0; i < 32; ++i) {
    const int t = half * 32 + i;
    const float e = __shfl(e0, t, 64);
    const f4v vv = v4s[t * 32 + l32];    // 16B/lane perfect stride
    o += e * vv;
  }
  // combine halves: lanes 0..31 add lane+32's partial
  o.x += __shfl(o.x, lane + 32, 64);
  o.y += __shfl(o.y, lane + 32, 64);
  o.z += __shfl(o.z, lane + 32, 64);
  o.w += __shfl(o.w, lane + 32, 64);

  const int pc = (kvh * 4 + wave) * NCHUNK + chunk;
  if (lane == 0) {
    ws[WS_M + pc] = m;
    ws[WS_L + pc] = l;
  }
  if (lane < 32)
    ((f4v*)(ws + WS_O + (size_t)pc * HD))[l32] = o;
}

// ---------------------------------------------------------------------------
// K3: combine 64 chunk-partials per q head + fresh token, normalize.
// grid = 32 heads, block = 128 (one thread per dim).
// ---------------------------------------------------------------------------
__global__ __launch_bounds__(128) void attn_reduce_kernel(float* __restrict__ ws)
{
  const int qh  = blockIdx.x;
  const int d   = threadIdx.x;
  const int kvh = qh >> 2;

  __shared__ float red[128];
  red[d] = ws[WS_Q + qh * HD + d] * ws[WS_K + kvh * HD + d];
  __syncthreads();
  for (int off = 64; off > 0; off >>= 1) {
    if (d < off) red[d] += red[d + off];
    __syncthreads();
  }
  const float s_new = red[0] * SCALE;

  float m_g = s_new;
#pragma unroll 8
  for (int c = 0; c < NCHUNK; ++c)
    m_g = fmaxf(m_g, ws[WS_M + qh * NCHUNK + c]);

  const float w_new = __expf(s_new - m_g);
  float l_g = w_new;
  float o_d = w_new * ws[WS_V + kvh * HD + d];
#pragma unroll 8
  for (int c = 0; c < NCHUNK; ++c) {
    const float mc = ws[WS_M + qh * NCHUNK + c];
    const float lc = ws[WS_L + qh * NCHUNK + c];
    const float w  = __expf(mc - m_g);
    l_g += lc * w;
    o_d += w * ws[WS_O + (size_t)(qh * NCHUNK + c) * HD + d];
  }
  ws[WS_AO + qh * HD + d] = o_d / l_g;
}

// ---------------------------------------------------------------------------
// K4: output projection GEMV, row pair per wave. grid = 512 blocks.
// ---------------------------------------------------------------------------
__global__ __launch_bounds__(256) void oproj_kernel(
    const float* __restrict__ wo,
    const float* __restrict__ ws,
    float* __restrict__ out)
{
  const int tid  = threadIdx.x;
  const int wave = tid >> 6;
  const int lane = tid & 63;
  const int pair = blockIdx.x * 4 + wave;   // 0..2047
  const int r0   = pair * 2;

  const float* w0 = wo + (size_t)r0 * DIM;
  const float* w1 = wo + (size_t)(r0 + 1) * DIM;
  const f4v*   a4 = (const f4v*)(ws + WS_AO);

  f4v v0 = (f4v)0.f, v1 = (f4v)0.f;
#pragma unroll 8
  for (int i = 0; i < 16; ++i) {
    const int o = (lane + i * 64) * 4;
    const f4v a  = a4[lane + i * 64];
    const f4v b0 = ntload4(w0 + o);
    const f4v b1 = ntload4(w1 + o);
    v0 += a * b0;
    v1 += a * b1;
  }
  float acc0 = v0.x + v0.y + v0.z + v0.w;
  float acc1 = v1.x + v1.y + v1.z + v1.w;
#pragma unroll
  for (int off = 32; off > 0; off >>= 1) {
    acc0 += __shfl_xor(acc0, off, 64);
    acc1 += __shfl_xor(acc1, off, 64);
  }

  if (lane == 0) {
    out[r0]     = acc0;
    out[r0 + 1] = acc1;
  }
}

// ---------------------------------------------------------------------------
extern "C" void kernel_launch(void* const* d_in, const int* in_sizes, int n_in,
                              void* d_out, int out_size, void* d_ws, size_t ws_size,
                              hipStream_t stream)
{
  const float* x    = (const float*)d_in[0];
  const float* fcos = (const float*)d_in[1];
  const float* fsin = (const float*)d_in[2];
  const float* wq   = (const float*)d_in[3];
  const float* wk   = (const float*)d_in[4];
  const float* wv   = (const float*)d_in[5];
  const float* wo   = (const float*)d_in[6];
  const float* kc   = (const float*)d_in[7];
  const float* vc   = (const float*)d_in[8];
  const int*   bidx = (const int*)d_in[9];
  float* out = (float*)d_out;
  float* ws  = (float*)d_ws;

  qkv_rope_kernel<<<768, 256, 0, stream>>>(x, wq, wk, wv, fcos, fsin, ws);
  attn_partial_kernel<<<dim3(NCHUNK, NKV), 256, 0, stream>>>(kc, vc, bidx, ws);
  attn_reduce_kernel<<<32, 128, 0, stream>>>(ws);
  oproj_kernel<<<512, 256, 0, stream>>>(wo, ws, out);
}